// Round 5
// baseline (309.978 us; speedup 1.0000x reference)
//
#include <hip/hip_runtime.h>
#include <stdint.h>

// ---------------------------------------------------------------------------
// SelfAttention: LN -> QKV (bf16 MFMA GEMM) -> S=QK^T/32 -> softmax -> att*V
// B=4, N=2048, D=H=1024. Outputs: att fp32 [4,2048,2048] ++ out fp32 [4,2048,1024]
// R9: fine-phase (m201-style) schedule for ALL GEMMs. Each phase:
//   [1 half-tile stage][<=12 ds_read_b128] s_bar; lgkmcnt(0); sched_barrier(0);
//   setprio(1) 16 MFMA setprio(0); [counted vmw at 2 phases per 2 tiles] s_bar.
//   - k_qkv   BN=192: 6 phases/2 tiles, grid 512 = 2 uniform rounds, vmw<4>@P3,P6
//   - k_scores BN=256: 8 phases/2 tiles, grid 256 = 1/CU,            vmw<6>@P4,P8
//   - k_out   BN=128 (4Mx2N waves, per-wave 64x64): 4 phases/2 tiles, vmw<4>@P2,P4
//   Stage->phase maps WAR-proven (stage issues only after the post-MFMA barrier
//   of the phase that last reads that LDS region); RAW via counted vmcnt before
//   the barrier preceding the first read of the staged tile. Even tiles -> buf E,
//   odd -> buf O (fixed). Overflow stages (kt>=NT) land in an 8KB trash region
//   with identical op counts so vmcnt arithmetic is unchanged.
// ---------------------------------------------------------------------------

typedef __attribute__((ext_vector_type(8))) short short8;   // 8 bf16 (4 VGPRs)
typedef __attribute__((ext_vector_type(4))) float floatx4;  // MFMA acc
typedef __attribute__((ext_vector_type(4))) uint16_t u16x4;

__device__ __forceinline__ uint16_t f2bf(float f) {
    union { float f; uint32_t u; } v; v.f = f;
    uint32_t r = v.u + 0x7fffu + ((v.u >> 16) & 1u);  // RNE
    return (uint16_t)(r >> 16);
}

// async global->LDS, 16B per lane. LDS dest is wave-uniform base + lane*16.
typedef const uint32_t __attribute__((address_space(1)))* gas1_t;
typedef uint32_t __attribute__((address_space(3)))* las3_t;
__device__ __forceinline__ void gload_lds16(const uint16_t* g, uint16_t* l) {
    __builtin_amdgcn_global_load_lds((gas1_t)g, (las3_t)l, 16, 0, 0);
}

__device__ __forceinline__ void s_bar()  { asm volatile("s_barrier" ::: "memory"); }
__device__ __forceinline__ void lgkm0()  { asm volatile("s_waitcnt lgkmcnt(0)" ::: "memory"); }
template<int N> __device__ __forceinline__ void vmw() {
    asm volatile("s_waitcnt vmcnt(%0)" :: "n"(N) : "memory");
}

// ---------------------------------------------------------------------------
// gemm8p<BN,EPI>: C = A * Bt^T. A:[M,K] bf16 rm, Bt:[N,K] bf16 rm. BM=256.
// 512 thr = 8 waves. BN=256/192: 2Mx4N waves (per-wave 128x64 / 128x48).
// BN=128: 4Mx2N waves (per-wave 64x64). BK=64 (2 K=32 halves ks0/ks1).
// LDS: 2 x (A 16384 + B BN*64) elems + 4096 trash.
// 16B-seg XOR swizzle (phys_seg = seg ^ (row&7)) via pre-swizzled global src +
// linear LDS dest; readers XOR the same -> 0 bank conflicts (proven R4-R8).
// EPI 0: fp32 store * alpha.  EPI 1: fused-qkv bf16 + bias, 3072-wide cols
//        de-interleave into q|k|v planes of 8192x1024.
// ---------------------------------------------------------------------------

#define RA(P, MF, MI)                                                     \
    { Af[(MF)][0] = *(const short8*)((P) + aoff + (MI) * 1024 + ksg0);    \
      Af[(MF)][1] = *(const short8*)((P) + aoff + (MI) * 1024 + ksg1); }
#define RB(P, NI)                                                         \
    { Bf[(NI)][0] = *(const short8*)((P) + ABUF + boff + (NI) * 1024 + ksg0); \
      Bf[(NI)][1] = *(const short8*)((P) + ABUF + boff + (NI) * 1024 + ksg1); }
// 16-MFMA cluster: acc rows MA..MA+3 from frag regs MF..MF+3, ni NI0..NI0+1
#define CLUST(MA, MF, NI0)                                                \
    __builtin_amdgcn_s_setprio(1);                                        \
    _Pragma("unroll") for (int mi = 0; mi < 4; ++mi)                      \
    _Pragma("unroll") for (int nn = 0; nn < 2; ++nn)                      \
    _Pragma("unroll") for (int ks = 0; ks < 2; ++ks)                      \
        acc[(MA) + mi][(NI0) + nn] =                                      \
            __builtin_amdgcn_mfma_f32_16x16x32_bf16(                      \
                Af[(MF) + mi][ks], Bf[(NI0) + nn][ks],                    \
                acc[(MA) + mi][(NI0) + nn], 0, 0, 0);                     \
    __builtin_amdgcn_s_setprio(0);
// 16-MFMA cluster: all 8 frag rows x single ni (BN=192 only)
#define CLUST1(NI)                                                        \
    __builtin_amdgcn_s_setprio(1);                                        \
    _Pragma("unroll") for (int mi = 0; mi < 8; ++mi)                      \
    _Pragma("unroll") for (int ks = 0; ks < 2; ++ks)                      \
        acc[mi][(NI)] = __builtin_amdgcn_mfma_f32_16x16x32_bf16(          \
            Af[mi][ks], Bf[(NI)][ks], acc[mi][(NI)], 0, 0, 0);            \
    __builtin_amdgcn_s_setprio(0);
// phase midpoint: barrier, drain own ds_reads, fence MFMA hoisting (rule #18)
#define PH_MID() s_bar(); lgkm0(); __builtin_amdgcn_sched_barrier(0)

template<int BN, int EPI>
__device__ __forceinline__ void gemm8p(
    const uint16_t* __restrict__ A, const uint16_t* __restrict__ Bt,
    const int K, const int NT, const int m0, const int n0,
    float* __restrict__ Cf, uint16_t* __restrict__ Cb, const int ldc,
    const float* __restrict__ bq, const float* __restrict__ bk,
    const float* __restrict__ bv, const float alpha)
{
    constexpr int ABUF  = 16384;               // A elems per buffer (256x64)
    constexpr int BBUF  = BN * 64;
    constexpr int BUFSZ = ABUF + BBUF;
    constexpr int WN    = (BN == 128) ? 2 : 4;
    constexpr int WM    = 8 / WN;
    constexpr int MIW   = 256 / (16 * WM);     // 8 or 4
    constexpr int NIW   = BN / (16 * WN);      // 4, 3, 4
    constexpr int NFRA  = (BN == 256) ? 4 : MIW;
    __shared__ uint16_t sm[2 * BUFSZ + 4096];
    uint16_t* const trash = sm + 2 * BUFSZ;
    const uint16_t* const E = sm;              // even tiles
    const uint16_t* const O = sm + BUFSZ;      // odd tiles

    const int t = threadIdx.x;

    // ---- staging geometry: thread t covers row t>>3, swizzled 16B-seg ----
    const int srow = t >> 3;
    const int sseg = (t & 7) ^ (srow & 7);
    const uint16_t* gA = A + (size_t)(m0 + srow) * K + sseg * 8;
    const uint16_t* gB = Bt + (size_t)(n0 + srow) * K + sseg * 8;

    // stage A rows h*128..h*128+127 of K-tile kt into buffer b (2 gloads)
    auto STGA = [&](int kt, int b, int h) {
        const bool lv = kt < NT;
        const size_t ko = (size_t)(lv ? kt : 0) * 64;
        uint16_t* d0 = lv ? (sm + b * BUFSZ + h * 8192 + t * 8) : (trash + t * 8);
        uint16_t* d1 = lv ? (sm + b * BUFSZ + h * 8192 + 4096 + t * 8) : (trash + t * 8);
        gload_lds16(gA + (size_t)(h * 128) * K + ko, d0);
        gload_lds16(gA + (size_t)(h * 128 + 64) * K + ko, d1);
    };
    // stage B 64-row units u0..u0+nu-1 of K-tile kt into buffer b (nu gloads)
    auto STGB = [&](int kt, int b, int u0, int nu) {
        const bool lv = kt < NT;
        const size_t ko = (size_t)(lv ? kt : 0) * 64;
#pragma unroll
        for (int p = 0; p < 4; ++p) {
            if (p < nu) {
                uint16_t* d = lv ? (sm + b * BUFSZ + ABUF + (u0 + p) * 4096 + t * 8)
                                 : (trash + t * 8);
                gload_lds16(gB + (size_t)((u0 + p) * 64) * K + ko, d);
            }
        }
    };

    // ---- reader geometry ----
    const int lane = t & 63;
    const int wid  = t >> 6;
    const int wm   = wid / WN;
    const int wn   = wid % WN;
    const int quad = lane >> 4;
    const int lrow = lane & 15;
    const int swz  = lrow & 7;
    const int ksg0 = (quad ^ swz) * 8;
    const int ksg1 = ((4 + quad) ^ swz) * 8;
    const int aoff = (wm * (16 * MIW) + lrow) * 64;
    const int boff = (wn * (16 * NIW) + lrow) * 64;

    floatx4 acc[MIW][NIW];
#pragma unroll
    for (int mi = 0; mi < MIW; ++mi)
#pragma unroll
        for (int ni = 0; ni < NIW; ++ni)
            acc[mi][ni] = floatx4{0.f, 0.f, 0.f, 0.f};

    short8 Af[NFRA][2];
    short8 Bf[NIW][2];

    if constexpr (BN == 256) {
        // prologue: t0 complete (8), t1 B-lo+A-lo+B-hi (6); drain t0
        STGB(0, 0, 0, 2); STGA(0, 0, 0); STGB(0, 0, 2, 2); STGA(0, 0, 1);
        STGB(1, 1, 0, 2); STGA(1, 1, 0); STGB(1, 1, 2, 2);
        vmw<6>(); s_bar();
        for (int te = 0; te < NT; te += 2) {
            // P1: stage A-hi(t+1)->O; read A-lo,B0-1 of E
            STGA(te + 1, 1, 1);
            RA(E, 0, 0) RA(E, 1, 1) RA(E, 2, 2) RA(E, 3, 3) RB(E, 0) RB(E, 1)
            PH_MID(); CLUST(0, 0, 0); s_bar();
            // P2: read B2-3
            RB(E, 2) RB(E, 3)
            PH_MID(); CLUST(0, 0, 2); s_bar();
            // P3: stage B-lo(t+2)->E (B(t) dead after P2); read A-hi (reg reuse)
            STGB(te + 2, 0, 0, 2);
            RA(E, 0, 4) RA(E, 1, 5) RA(E, 2, 6) RA(E, 3, 7)
            PH_MID(); CLUST(4, 0, 0); s_bar();
            // P4: stage A-lo+B-hi(t+2)->E (A(t) dead after P3); vmw -> t+1 landed
            STGA(te + 2, 0, 0); STGB(te + 2, 0, 2, 2);
            PH_MID(); CLUST(4, 0, 2); vmw<6>(); s_bar();
            // P5-P8: mirror on O, staging rest of t+2 then t+3
            STGA(te + 2, 0, 1);
            RA(O, 0, 0) RA(O, 1, 1) RA(O, 2, 2) RA(O, 3, 3) RB(O, 0) RB(O, 1)
            PH_MID(); CLUST(0, 0, 0); s_bar();
            RB(O, 2) RB(O, 3)
            PH_MID(); CLUST(0, 0, 2); s_bar();
            STGB(te + 3, 1, 0, 2);
            RA(O, 0, 4) RA(O, 1, 5) RA(O, 2, 6) RA(O, 3, 7)
            PH_MID(); CLUST(4, 0, 0); s_bar();
            STGA(te + 3, 1, 0); STGB(te + 3, 1, 2, 2);
            PH_MID(); CLUST(4, 0, 2); vmw<6>(); s_bar();
        }
    } else if constexpr (BN == 192) {
        // prologue: t0 (7), t1 A (4); drain t0
        STGA(0, 0, 0); STGA(0, 0, 1); STGB(0, 0, 0, 3);
        STGA(1, 1, 0); STGA(1, 1, 1);
        vmw<4>(); s_bar();
        for (int te = 0; te < NT; te += 2) {
            // P1: stage B(t+1)->O (B(t-1) dead after prev-P6); read A0-3,B0-1
            STGB(te + 1, 1, 0, 3);
            RA(E, 0, 0) RA(E, 1, 1) RA(E, 2, 2) RA(E, 3, 3) RB(E, 0) RB(E, 1)
            PH_MID(); CLUST(0, 0, 0); s_bar();
            // P2: read A4-7
            RA(E, 4, 4) RA(E, 5, 5) RA(E, 6, 6) RA(E, 7, 7)
            PH_MID(); CLUST(4, 4, 0); s_bar();
            // P3: stage A(t+2)->E (A(t) dead after P2); read B2; vmw -> t+1 landed
            STGA(te + 2, 0, 0); STGA(te + 2, 0, 1);
            RB(E, 2)
            PH_MID(); CLUST1(2); vmw<4>(); s_bar();
            // P4-P6: mirror on O
            STGB(te + 2, 0, 0, 3);
            RA(O, 0, 0) RA(O, 1, 1) RA(O, 2, 2) RA(O, 3, 3) RB(O, 0) RB(O, 1)
            PH_MID(); CLUST(0, 0, 0); s_bar();
            RA(O, 4, 4) RA(O, 5, 5) RA(O, 6, 6) RA(O, 7, 7)
            PH_MID(); CLUST(4, 4, 0); s_bar();
            STGA(te + 3, 1, 0); STGA(te + 3, 1, 1);
            RB(O, 2)
            PH_MID(); CLUST1(2); vmw<4>(); s_bar();
        }
    } else {  // BN == 128, 4Mx2N waves
        // prologue: t0 (6), t1 A (4); drain t0
        STGA(0, 0, 0); STGA(0, 0, 1); STGB(0, 0, 0, 2);
        STGA(1, 1, 0); STGA(1, 1, 1);
        vmw<4>(); s_bar();
        for (int te = 0; te < NT; te += 2) {
            // P1: stage B(t+1)->O; read A0-3,B0-1 of E
            STGB(te + 1, 1, 0, 2);
            RA(E, 0, 0) RA(E, 1, 1) RA(E, 2, 2) RA(E, 3, 3) RB(E, 0) RB(E, 1)
            PH_MID(); CLUST(0, 0, 0); s_bar();
            // P2: stage A(t+2)->E (A(t) dead after P1); read B2-3; vmw -> t+1
            STGA(te + 2, 0, 0); STGA(te + 2, 0, 1);
            RB(E, 2) RB(E, 3)
            PH_MID(); CLUST(0, 0, 2); vmw<4>(); s_bar();
            // P3-P4: mirror on O
            STGB(te + 2, 0, 0, 2);
            RA(O, 0, 0) RA(O, 1, 1) RA(O, 2, 2) RA(O, 3, 3) RB(O, 0) RB(O, 1)
            PH_MID(); CLUST(0, 0, 0); s_bar();
            STGA(te + 3, 1, 0); STGA(te + 3, 1, 1);
            RB(O, 2) RB(O, 3)
            PH_MID(); CLUST(0, 0, 2); vmw<4>(); s_bar();
        }
    }

    vmw<0>();  // drain trailing trash stages

    // ---- epilogue: C/D layout col=lane&15, row=quad*4+reg [m89/m91] ----
    const int rbase = m0 + wm * (16 * MIW) + quad * 4;
    const int cbase = n0 + wn * (16 * NIW) + lrow;

    if constexpr (EPI == 1) {
        float bc[NIW];
#pragma unroll
        for (int ni = 0; ni < NIW; ++ni) {
            const int col = cbase + ni * 16;
            const int z = col >> 10;
            const float* bp = (z == 0) ? bq : ((z == 1) ? bk : bv);
            bc[ni] = bp[col & 1023];
        }
#pragma unroll
        for (int mi = 0; mi < MIW; ++mi) {
#pragma unroll
            for (int ni = 0; ni < NIW; ++ni) {
                const int row = rbase + mi * 16;
                const int col = cbase + ni * 16;
                const int z = col >> 10, h = col & 1023;
#pragma unroll
                for (int r = 0; r < 4; ++r)
                    Cb[(size_t)z * 8388608 + (size_t)(row + r) * 1024 + h] =
                        f2bf(acc[mi][ni][r] + bc[ni]);
            }
        }
    } else {
#pragma unroll
        for (int mi = 0; mi < MIW; ++mi) {
#pragma unroll
            for (int ni = 0; ni < NIW; ++ni) {
                const int row = rbase + mi * 16;
                const int col = cbase + ni * 16;
#pragma unroll
                for (int r = 0; r < 4; ++r)
                    Cf[(size_t)(row + r) * ldc + col] = acc[mi][ni][r] * alpha;
            }
        }
    }
}

// q|k|v = xn @ [wq|wk|wv]^T + bias, one GEMM M=8192 N=3072 K=1024, BN=192.
__global__ __launch_bounds__(512, 2) void k_qkv(
    const uint16_t* __restrict__ xn, const uint16_t* __restrict__ wt,
    const float* __restrict__ bq, const float* __restrict__ bk,
    const float* __restrict__ bv, uint16_t* __restrict__ qkv)
{
    // grid (16, 32) = 512 blocks -> 2 uniform rounds; bijective XCD swizzle
    const int flat = blockIdx.y * 16 + blockIdx.x;
    const int s = (flat & 7) * 64 + (flat >> 3);
    const int bx = s & 15, by = s >> 4;
    gemm8p<192, 1>(xn, wt, 1024, 16, by * 256, bx * 192,
                   nullptr, qkv, 0, bq, bk, bv, 0.f);
}

// S = q @ k^T * (1/32), fp32 into d_out att region. BN=256, grid 256 = 1/CU.
__global__ __launch_bounds__(512, 2) void k_scores(
    const uint16_t* __restrict__ q, const uint16_t* __restrict__ k,
    float* __restrict__ S)
{
    const int flat = blockIdx.z * 64 + blockIdx.y * 8 + blockIdx.x;
    const int s = (flat & 7) * 32 + (flat >> 3);        // 256-bijective
    const int z = s >> 6, y = (s >> 3) & 7, x = s & 7;
    gemm8p<256, 0>(q + (size_t)z * 2048 * 1024, k + (size_t)z * 2048 * 1024,
                   1024, 16, y * 256, x * 256,
                   S + (size_t)z * 2048 * 2048, nullptr, 2048,
                   nullptr, nullptr, nullptr, 0.03125f);
}

// out = att_bf16 @ vt^T, fp32. BN=128 (4Mx2N), K=2048, grid 256 = 1/CU.
__global__ __launch_bounds__(512, 2) void k_out(
    const uint16_t* __restrict__ attb, const uint16_t* __restrict__ vt,
    float* __restrict__ out)
{
    const int flat = blockIdx.z * 64 + blockIdx.y * 8 + blockIdx.x;
    const int s = (flat & 7) * 32 + (flat >> 3);        // 256-bijective
    const int z = s >> 6, y = (s >> 3) & 7, x = s & 7;
    gemm8p<128, 0>(attb + (size_t)z * 2048 * 2048, vt + (size_t)z * 1024 * 2048,
                   2048, 32, y * 256, x * 128,
                   out + (size_t)z * 2048 * 1024, nullptr, 1024,
                   nullptr, nullptr, nullptr, 1.0f);
}

// ---------------------------------------------------------------------------
// LayerNorm rows of x[8192][1024] -> bf16 xn
// ---------------------------------------------------------------------------
__global__ __launch_bounds__(256) void k_ln(
    const float* __restrict__ x, const float* __restrict__ lw,
    const float* __restrict__ lb, uint16_t* __restrict__ xn)
{
    const int row = blockIdx.x;
    const int t = threadIdx.x;
    const float* xr = x + (size_t)row * 1024;
    const float4 xv = ((const float4*)xr)[t];
    float s  = xv.x + xv.y + xv.z + xv.w;
    float s2 = xv.x * xv.x + xv.y * xv.y + xv.z * xv.z + xv.w * xv.w;
#pragma unroll
    for (int off = 32; off > 0; off >>= 1) {
        s  += __shfl_xor(s, off);
        s2 += __shfl_xor(s2, off);
    }
    __shared__ float ps[4], ps2[4];
    const int w = t >> 6, lane = t & 63;
    if (lane == 0) { ps[w] = s; ps2[w] = s2; }
    __syncthreads();
    s  = ps[0] + ps[1] + ps[2] + ps[3];
    s2 = ps2[0] + ps2[1] + ps2[2] + ps2[3];
    const float mu  = s * (1.f / 1024.f);
    const float var = s2 * (1.f / 1024.f) - mu * mu;
    const float rs  = rsqrtf(var + 1e-5f);
    const float4 wv = ((const float4*)lw)[t];
    const float4 bv = ((const float4*)lb)[t];
    u16x4 o;
    o.x = f2bf((xv.x - mu) * rs * wv.x + bv.x);
    o.y = f2bf((xv.y - mu) * rs * wv.y + bv.y);
    o.z = f2bf((xv.z - mu) * rs * wv.z + bv.z);
    o.w = f2bf((xv.w - mu) * rs * wv.w + bv.w);
    ((u16x4*)(xn + (size_t)row * 1024))[t] = o;
}

// ---------------------------------------------------------------------------
// Transpose + cast weights: w[1024][1024] fp32 -> wt[1024][1024] bf16 (wt[h][d])
// ---------------------------------------------------------------------------
__global__ void k_wt(const float* __restrict__ wq, const float* __restrict__ wk,
                     const float* __restrict__ wv, uint16_t* __restrict__ wt)
{
    __shared__ float tile[32][33];
    const int z = blockIdx.z;
    const float* W = (z == 0) ? wq : ((z == 1) ? wk : wv);
    uint16_t* T = wt + (size_t)z * 1024 * 1024;
    const int c0 = blockIdx.x * 32, r0 = blockIdx.y * 32;
    const int tx = threadIdx.x, ty = threadIdx.y;  // (32,8)
#pragma unroll
    for (int i = 0; i < 4; i++)
        tile[ty + 8 * i][tx] = W[(size_t)(r0 + ty + 8 * i) * 1024 + c0 + tx];
    __syncthreads();
#pragma unroll
    for (int i = 0; i < 4; i++)
        T[(size_t)(c0 + ty + 8 * i) * 1024 + r0 + tx] = f2bf(tile[tx][ty + 8 * i]);
}

// ---------------------------------------------------------------------------
// Transpose v bf16 [2048][1024] -> vt [1024][2048] per batch.
// ---------------------------------------------------------------------------
__global__ __launch_bounds__(256) void k_vt(
    const uint16_t* __restrict__ v, uint16_t* __restrict__ vt)
{
    __shared__ uint16_t tile[64][68];
    const int b = blockIdx.z;
    const uint16_t* V = v + (size_t)b * 2048 * 1024;
    uint16_t* T = vt + (size_t)b * 1024 * 2048;
    const int h0 = blockIdx.x * 64, t0 = blockIdx.y * 64;
    const int t = threadIdx.x;
    const int rr = t >> 4;
    const int cc = (t & 15) * 4;
#pragma unroll
    for (int i = 0; i < 4; i++) {
        const int tok = rr + 16 * i;
        *(u16x4*)&tile[tok][cc] =
            *(const u16x4*)&V[(size_t)(t0 + tok) * 1024 + h0 + cc];
    }
    __syncthreads();
#pragma unroll
    for (int i = 0; i < 4; i++) {
        const int h = rr + 16 * i;
        u16x4 o;
        o.x = tile[cc + 0][h];
        o.y = tile[cc + 1][h];
        o.z = tile[cc + 2][h];
        o.w = tile[cc + 3][h];
        *(u16x4*)&T[(size_t)(h0 + h) * 2048 + t0 + cc] = o;
    }
}

// ---------------------------------------------------------------------------
// Row softmax over S[8192][2048] fp32 (in place) + bf16 copy for the PV GEMM
// ---------------------------------------------------------------------------
__global__ __launch_bounds__(256) void k_softmax(
    float* __restrict__ S, uint16_t* __restrict__ attb)
{
    const size_t row = blockIdx.x;
    float* p = S + row * 2048;
    const int t = threadIdx.x;
    float4 a = ((float4*)p)[2 * t];
    float4 b = ((float4*)p)[2 * t + 1];
    float m = fmaxf(fmaxf(fmaxf(a.x, a.y), fmaxf(a.z, a.w)),
                    fmaxf(fmaxf(b.x, b.y), fmaxf(b.z, b.w)));
#pragma unroll
    for (int off = 32; off > 0; off >>= 1) m = fmaxf(m, __shfl_xor(m, off));
    __shared__ float pm[4], pl[4];
    const int w = t >> 6, lane = t & 63;
    if (lane == 0) pm[w] = m;
    __syncthreads();
    m = fmaxf(fmaxf(pm[0], pm[1]), fmaxf(pm[2], pm[3]));

    a.x = __expf(a.x - m); a.y = __expf(a.y - m);
    a.z = __expf(a.z - m); a.w = __expf(a.w - m);
    b.x = __expf(b.x - m); b.y = __expf(b.y - m);
    b.z = __expf(b.z - m); b.w = __expf(b.w - m);
    float s = a.x + a.y + a.z + a.w + b.x + b.y + b.z + b.w;
#pragma unroll
    for (int off = 32; off > 0; off >>= 1) s += __shfl_xor(s, off);
    if (lane == 0) pl[w] = s;
    __syncthreads();
    s = pl[0] + pl[1] + pl[2] + pl[3];
    const float inv = 1.f / s;

    a.x *= inv; a.y *= inv; a.z *= inv; a.w *= inv;
    b.x *= inv; b.y *= inv; b.z *= inv; b.w *= inv;
    ((float4*)p)[2 * t]     = a;
    ((float4*)p)[2 * t + 1] = b;

    uint16_t* q = attb + row * 2048 + t * 8;
    u16x4 o0, o1;
    o0.x = f2bf(a.x); o0.y = f2bf(a.y); o0.z = f2bf(a.z); o0.w = f2bf(a.w);
    o1.x = f2bf(b.x); o1.y = f2bf(b.y); o1.z = f2bf(b.z); o1.w = f2bf(b.w);
    ((u16x4*)q)[0] = o0;
    ((u16x4*)q)[1] = o1;
}

// ---------------------------------------------------------------------------
extern "C" void kernel_launch(void* const* d_in, const int* in_sizes, int n_in,
                              void* d_out, int out_size, void* d_ws, size_t ws_size,
                              hipStream_t stream)
{
    const float* x  = (const float*)d_in[0];
    const float* wq = (const float*)d_in[1];
    const float* bq = (const float*)d_in[2];
    const float* wk = (const float*)d_in[3];
    const float* bk = (const float*)d_in[4];
    const float* wv = (const float*)d_in[5];
    const float* bv = (const float*)d_in[6];
    const float* lw = (const float*)d_in[7];
    const float* lb = (const float*)d_in[8];

    float* att = (float*)d_out;                         // [4][2048][2048] = 64 MB
    float* out = (float*)d_out + (size_t)16777216;      // [4][2048][1024] = 32 MB

    // Scratch inside d_out's att region (dead until k_scores writes all of it):
    uint16_t* xn = (uint16_t*)d_out;                    // 8,388,608 elems (16.8 MB)
    uint16_t* wt = (uint16_t*)d_out + (size_t)8388608;  // 3,145,728 elems (6.3 MB)

    // ws layout (uint16 elems), exactly q+k+v = 25,165,824 elems = 50,331,648 B:
    uint16_t* ws   = (uint16_t*)d_ws;
    uint16_t* q    = ws;
    uint16_t* k    = ws + (size_t)8388608;
    uint16_t* v    = ws + (size_t)2 * 8388608;
    uint16_t* vt   = ws;                                // overlays dead q
    uint16_t* attb = ws + (size_t)8388608;              // overlays dead k+v
    uint16_t* qkv  = q;

    if (ws_size < (size_t)50331648) return;  // OOB guard: fail clean, not crash

    k_ln<<<8192, 256, 0, stream>>>(x, lw, lb, xn);
    k_wt<<<dim3(32, 32, 3), dim3(32, 8), 0, stream>>>(wq, wk, wv, wt);
    k_qkv<<<dim3(16, 32), 512, 0, stream>>>(xn, wt, bq, bk, bv, qkv);
    k_scores<<<dim3(8, 8, 4), 512, 0, stream>>>(q, k, att);     // frees q,k
    k_vt<<<dim3(16, 32, 4), 256, 0, stream>>>(v, vt);           // vt over dead q
    k_softmax<<<8192, 256, 0, stream>>>(att, attb);             // attb over dead k+v
    k_out<<<dim3(8, 8, 4), 512, 0, stream>>>(attb, vt, out);
}